// Round 7
// baseline (925.254 us; speedup 1.0000x reference)
//
#include <hip/hip_runtime.h>

#define DM 1024
typedef unsigned short u16;
typedef __attribute__((ext_vector_type(8))) short short8;
typedef __attribute__((ext_vector_type(4))) float f32x4;

__device__ __forceinline__ float4 ldg4(const float* p) {
    return *reinterpret_cast<const float4*>(p);
}

// split f32 -> bf16 hi (truncated) + bf16 lo (residual). x ~= hi+lo, rel err ~2^-16.
__device__ __forceinline__ void split2(float x, u16& hi, u16& lo) {
    unsigned u = __float_as_uint(x);
    hi = (u16)(u >> 16);
    float hif = __uint_as_float(u & 0xffff0000u);
    lo = (u16)(__float_as_uint(x - hif) >> 16);
}

// round-to-nearest-even bf16
__device__ __forceinline__ u16 bf16rn(float x) {
    unsigned u = __float_as_uint(x);
    return (u16)((u + 0x7fffu + ((u >> 16) & 1u)) >> 16);
}

// T2 swizzle, 32-col granularity (BK=32 compatible): XOR the 8-u16 granule
// index within each 32-u16 block by (row>>1)&3. 2 rows/bank-quad = 2-way = free.
__device__ __forceinline__ int swz32(int row, int col) {
    return (col & ~31) | ((((col >> 3) & 3) ^ ((row >> 1) & 3)) << 3) | (col & 7);
}

// async global->LDS, 16B per lane (dest = uniform base + lane*16)
__device__ __forceinline__ void gl_lds16(const u16* g, u16* l) {
    __builtin_amdgcn_global_load_lds(
        (const __attribute__((address_space(1))) void*)g,
        (__attribute__((address_space(3))) void*)l, 16, 0, 0);
}

// ---------------------------------------------------------------------------
// Activation pre-split: f32 [srcrows][1024] -> swz32 split hi/lo u16.
// ---------------------------------------------------------------------------
struct PJob { const float* src; int astride, aoff; u16* dh; u16* dl; };
struct PJobs { PJob j[5]; };

__global__ __launch_bounds__(256) void prep_k(PJobs js) {
    const PJob J = js.j[blockIdx.x >> 12];
    const int row = blockIdx.x & 4095;
    const int t = threadIdx.x;
    const size_t srow = (size_t)(row >> 10) * J.astride + (row & 1023) + J.aoff;
    float4 v = ldg4(J.src + srow * DM + t * 4);
    u16 h[4], l[4];
    split2(v.x, h[0], l[0]); split2(v.y, h[1], l[1]);
    split2(v.z, h[2], l[2]); split2(v.w, h[3], l[3]);
    ushort4 h4 = {h[0], h[1], h[2], h[3]};
    ushort4 l4 = {l[0], l[1], l[2], l[3]};
    const int c = swz32(row, t * 4);
    *reinterpret_cast<ushort4*>(J.dh + (size_t)row * DM + c) = h4;
    *reinterpret_cast<ushort4*>(J.dl + (size_t)row * DM + c) = l4;
}

// ---------------------------------------------------------------------------
// Weight transpose+split+swizzle: W[k][n] f32 -> Wt_hi/lo[n][swz32(n,k)].
// ---------------------------------------------------------------------------
struct WPack {
    const float* in[8];
    u16* hi[8];
    u16* lo[8];
};

__global__ __launch_bounds__(256) void convw_k(WPack p) {
    __shared__ float T[32][33];
    const int w = blockIdx.y;
    const int tr = blockIdx.x >> 5, tc = blockIdx.x & 31;
    const int t = threadIdx.x;
    {
        int lr = t >> 3, c4 = t & 7;
        float4 v = ldg4(p.in[w] + (size_t)(tr * 32 + lr) * DM + tc * 32 + c4 * 4);
        T[lr][c4 * 4 + 0] = v.x; T[lr][c4 * 4 + 1] = v.y;
        T[lr][c4 * 4 + 2] = v.z; T[lr][c4 * 4 + 3] = v.w;
    }
    __syncthreads();
    const int n = tc * 32 + (t >> 3);
    const int kb = tr * 32 + (t & 7) * 4;
    ushort4 h4, l4;
    u16 hh, ll;
    split2(T[(t & 7) * 4 + 0][t >> 3], hh, ll); h4.x = hh; l4.x = ll;
    split2(T[(t & 7) * 4 + 1][t >> 3], hh, ll); h4.y = hh; l4.y = ll;
    split2(T[(t & 7) * 4 + 2][t >> 3], hh, ll); h4.z = hh; l4.z = ll;
    split2(T[(t & 7) * 4 + 3][t >> 3], hh, ll); h4.w = hh; l4.w = ll;
    const int c = swz32(n, kb);
    *reinterpret_cast<ushort4*>(p.hi[w] + (size_t)n * DM + c) = h4;
    *reinterpret_cast<ushort4*>(p.lo[w] + (size_t)n * DM + c) = l4;
}

// mask f32 -> byte (0/1). 4 MB, L2/L3 resident thereafter.
__global__ __launch_bounds__(256) void mprep_k(
    const float* __restrict__ mask, unsigned char* __restrict__ m8)
{
    const size_t i = ((size_t)blockIdx.x * 256 + threadIdx.x) * 4;
    float4 v = ldg4(mask + i);
    uchar4 o = {(unsigned char)(v.x != 0.f), (unsigned char)(v.y != 0.f),
                (unsigned char)(v.z != 0.f), (unsigned char)(v.w != 0.f)};
    *reinterpret_cast<uchar4*>(m8 + i) = o;
}

// ---------------------------------------------------------------------------
// gemm7: 256x256-tile split-bf16 MFMA GEMM. BK=32, 8 waves (2x4 of 128x64),
// dbuf 2x64KB LDS (1 block/CU, 2 waves/SIMD), global_load_lds width=16,
// swz32 LDS (2-way = free). STAGE(kt+1) issued before COMPUTE(kt); one
// barrier per K-step. 2x arithmetic intensity per staged byte vs 128-tile.
// Natural blockIdx round-robin gives each XCD one bn-panel (L2-resident B).
// Multi-job: job = blockIdx.x >> 6 (64 blocks per job: 16 bm x 4 bn).
// ---------------------------------------------------------------------------
struct GJob {
    const u16 *Ah, *Al, *A2h, *A2l;
    const u16 *Bh, *Bl, *B2h, *B2l;
    const float *b1, *b2;
    float* Cf; u16 *Ch; u16 *Cl;
    int nt, act, outsplit, dualk;
};
struct GJobs { GJob j[3]; };

__global__ __launch_bounds__(512) void gemm7(GJobs js) {
    extern __shared__ u16 lds[];  // buf*32768 + {AH@0, AL@8192, BH@16384, BL@24576}
    const GJob J = js.j[blockIdx.x >> 6];
    const int bid = blockIdx.x & 63;
    const int t = threadIdx.x;
    const int bm = bid >> 2, bn = bid & 3;
    const int lane = t & 63, w = t >> 6;     // 8 waves
    const int wm = w >> 2, wn = w & 3;       // 2 x 4 wave grid (128x64 each)
    const int fr = lane & 15, fq = lane >> 4;

    // staging lane map: 16 rows per gl_lds; lane -> row=lane>>2, granule=lane&3
    const int sr = lane >> 2;
    const int sg = (lane & 3) * 8;
    const size_t gA0 = (size_t)(bm * 256 + w * 32 + sr) * DM + sg;
    const size_t gA1 = gA0 + (size_t)16 * DM;
    const size_t gB0 = (size_t)(bn * 256 + w * 32 + sr) * DM + sg;
    const size_t gB1 = gB0 + (size_t)16 * DM;
    const int l0 = (w * 32) * 32;            // wave's LDS row base (u16)

    f32x4 acc[8][4];
    #pragma unroll
    for (int i = 0; i < 8; ++i)
        #pragma unroll
        for (int j = 0; j < 4; ++j)
            acc[i][j] = (f32x4){0.f, 0.f, 0.f, 0.f};

    auto STAGE = [&](int kt, int buf) {
        const bool second = J.dualk && (kt >= 32);
        const int ekt = J.dualk ? (kt & 31) : kt;
        const u16* pAh = second ? J.A2h : J.Ah;
        const u16* pAl = second ? J.A2l : J.Al;
        const u16* pBh = second ? J.B2h : J.Bh;
        const u16* pBl = second ? J.B2l : J.Bl;
        const int ko = ekt * 32;
        u16* base = lds + buf * 32768;
        gl_lds16(pAh + gA0 + ko, base +         l0);
        gl_lds16(pAh + gA1 + ko, base +         l0 + 512);
        gl_lds16(pAl + gA0 + ko, base +  8192 + l0);
        gl_lds16(pAl + gA1 + ko, base +  8192 + l0 + 512);
        gl_lds16(pBh + gB0 + ko, base + 16384 + l0);
        gl_lds16(pBh + gB1 + ko, base + 16384 + l0 + 512);
        gl_lds16(pBl + gB0 + ko, base + 24576 + l0);
        gl_lds16(pBl + gB1 + ko, base + 24576 + l0 + 512);
    };

    auto COMPUTE = [&](int buf) {
        const u16* base = lds + buf * 32768;
        short8 ah[8], al[8];
        #pragma unroll
        for (int mi = 0; mi < 8; ++mi) {
            const int row = wm * 128 + mi * 16 + fr;
            const int off = row * 32 + ((fq ^ ((row >> 1) & 3)) << 3);
            ah[mi] = *reinterpret_cast<const short8*>(base + off);
            al[mi] = *reinterpret_cast<const short8*>(base + 8192 + off);
        }
        #pragma unroll
        for (int nj = 0; nj < 4; ++nj) {
            const int col = wn * 64 + nj * 16 + fr;
            const int off = col * 32 + ((fq ^ ((col >> 1) & 3)) << 3);
            short8 bh = *reinterpret_cast<const short8*>(base + 16384 + off);
            short8 bl = *reinterpret_cast<const short8*>(base + 24576 + off);
            #pragma unroll
            for (int mi = 0; mi < 8; ++mi) {
                acc[mi][nj] = __builtin_amdgcn_mfma_f32_16x16x32_bf16(ah[mi], bh, acc[mi][nj], 0, 0, 0);
                acc[mi][nj] = __builtin_amdgcn_mfma_f32_16x16x32_bf16(ah[mi], bl, acc[mi][nj], 0, 0, 0);
                acc[mi][nj] = __builtin_amdgcn_mfma_f32_16x16x32_bf16(al[mi], bh, acc[mi][nj], 0, 0, 0);
            }
        }
    };

    const int NT = J.nt;
    STAGE(0, 0);
    __syncthreads();
    for (int kt = 0; kt < NT; ++kt) {
        if (kt + 1 < NT) STAGE(kt + 1, (kt + 1) & 1);  // in flight under MFMAs
        COMPUTE(kt & 1);
        __syncthreads();
    }

    // C/D frag: col = lane&15, row = (lane>>4)*4 + rr (m89)
    #pragma unroll
    for (int nj = 0; nj < 4; ++nj) {
        const int col = bn * 256 + wn * 64 + nj * 16 + fr;
        float bv = J.b1[col];
        if (J.dualk) bv += J.b2[col];
        #pragma unroll
        for (int mi = 0; mi < 8; ++mi) {
            const int row0 = bm * 256 + wm * 128 + mi * 16 + fq * 4;
            #pragma unroll
            for (int rr = 0; rr < 4; ++rr) {
                float x = acc[mi][nj][rr] + bv;
                if (J.act) x = (x >= 0.f) ? x : 0.2f * x;
                const int row = row0 + rr;
                if (J.outsplit) {
                    u16 hh, ll;
                    split2(x, hh, ll);
                    const size_t off = (size_t)row * DM + swz32(row, col);
                    J.Ch[off] = hh;
                    J.Cl[off] = ll;
                } else {
                    J.Cf[(size_t)row * DM + col] = x;
                }
            }
        }
    }
}

// ---------------------------------------------------------------------------
// attn_a: rowsums only. QBLK=64, 4 waves, grid 1024, ~56KB static LDS,
// 2 blk/CU. Per tile: {B1; K write; B2; K(t+1) reg prefetch; QK^T 3-pass;
// exp+sum in FRAGMENT layout (no S bounce, byte mask)}. 2 barriers/tile.
// Output: rsg = 1/rowsum per (b,h,q).
// ---------------------------------------------------------------------------
__global__ __launch_bounds__(256) void attn_a(
    const float* __restrict__ qp, const float* __restrict__ kp,
    const unsigned char* __restrict__ m8, float* __restrict__ rsg)
{
    __shared__ u16 Qh[64 * 72], Ql[64 * 72], Kh[128 * 72], Kl[128 * 72];
    __shared__ float rs[2][64];

    const int t = threadIdx.x;
    const int lane = t & 63, w = t >> 6;
    const int wm = w >> 1, wn = w & 1;
    const int fr = lane & 15, fq = lane >> 4;
    const int blk = blockIdx.x;
    const int qt = blk & 15, hh = (blk >> 4) & 15, b = blk >> 8;
    const int q0 = qt * 64;

    const size_t qbase  = ((size_t)b * 1024 + q0) * DM + hh * 64;
    const size_t kvbase = ((size_t)b * 1024) * DM + hh * 64;
    const size_t mb8    = ((size_t)b) << 20;

    #pragma unroll
    for (int l = 0; l < 4; ++l) {
        int f = t + l * 256;
        int r = f >> 4, dq = f & 15;
        float4 v = ldg4(qp + qbase + (size_t)r * DM + dq * 4);
        u16 hi, lo; ushort4 h4, l4;
        split2(v.x, hi, lo); h4.x = hi; l4.x = lo;
        split2(v.y, hi, lo); h4.y = hi; l4.y = lo;
        split2(v.z, hi, lo); h4.z = hi; l4.z = lo;
        split2(v.w, hi, lo); h4.w = hi; l4.w = lo;
        *reinterpret_cast<ushort4*>(Qh + r * 72 + dq * 4) = h4;
        *reinterpret_cast<ushort4*>(Ql + r * 72 + dq * 4) = l4;
    }

    float rpart[2][4] = {};

    float4 kreg[8];
    #pragma unroll
    for (int l = 0; l < 8; ++l) {
        int f = t + l * 256;
        int r = f >> 4, dq = f & 15;
        kreg[l] = ldg4(kp + kvbase + (size_t)r * DM + dq * 4);
    }

    for (int kt2 = 0; kt2 < 8; ++kt2) {
        const int kb = kt2 * 128;
        __syncthreads();   // prev QK^T reads done
        #pragma unroll
        for (int l = 0; l < 8; ++l) {
            int f = t + l * 256;
            int r = f >> 4, dq = f & 15;
            float4 v = kreg[l];
            u16 hi, lo; ushort4 h4, l4;
            split2(v.x, hi, lo); h4.x = hi; l4.x = lo;
            split2(v.y, hi, lo); h4.y = hi; l4.y = lo;
            split2(v.z, hi, lo); h4.z = hi; l4.z = lo;
            split2(v.w, hi, lo); h4.w = hi; l4.w = lo;
            *reinterpret_cast<ushort4*>(Kh + r * 72 + dq * 4) = h4;
            *reinterpret_cast<ushort4*>(Kl + r * 72 + dq * 4) = l4;
        }
        __syncthreads();

        {
            const int nkb = (kt2 < 7 ? kt2 + 1 : 7) * 128;
            #pragma unroll
            for (int l = 0; l < 8; ++l) {
                int f = t + l * 256;
                int r = f >> 4, dq = f & 15;
                kreg[l] = ldg4(kp + kvbase + (size_t)(nkb + r) * DM + dq * 4);
            }
        }

        f32x4 accs[2][4];
        #pragma unroll
        for (int i = 0; i < 2; ++i)
            #pragma unroll
            for (int j = 0; j < 4; ++j)
                accs[i][j] = (f32x4){0.f, 0.f, 0.f, 0.f};
        #pragma unroll
        for (int kk = 0; kk < 2; ++kk) {
            short8 qh_[2], ql_[2];
            #pragma unroll
            for (int mi = 0; mi < 2; ++mi) {
                const int off = (wm * 32 + mi * 16 + fr) * 72 + kk * 32 + fq * 8;
                qh_[mi] = *reinterpret_cast<const short8*>(Qh + off);
                ql_[mi] = *reinterpret_cast<const short8*>(Ql + off);
            }
            #pragma unroll
            for (int nj = 0; nj < 4; ++nj) {
                const int off = (wn * 64 + nj * 16 + fr) * 72 + kk * 32 + fq * 8;
                short8 kh_ = *reinterpret_cast<const short8*>(Kh + off);
                short8 kl_ = *reinterpret_cast<const short8*>(Kl + off);
                #pragma unroll
                for (int mi = 0; mi < 2; ++mi) {
                    accs[mi][nj] = __builtin_amdgcn_mfma_f32_16x16x32_bf16(qh_[mi], kh_, accs[mi][nj], 0, 0, 0);
                    accs[mi][nj] = __builtin_amdgcn_mfma_f32_16x16x32_bf16(qh_[mi], kl_, accs[mi][nj], 0, 0, 0);
                    accs[mi][nj] = __builtin_amdgcn_mfma_f32_16x16x32_bf16(ql_[mi], kh_, accs[mi][nj], 0, 0, 0);
                }
            }
        }

        // exp + rowsum in fragment layout (no S bounce)
        #pragma unroll
        for (int mi = 0; mi < 2; ++mi)
            #pragma unroll
            for (int rr = 0; rr < 4; ++rr) {
                const int gq = q0 + wm * 32 + mi * 16 + fq * 4 + rr;
                const size_t mrow = mb8 + (size_t)gq * 1024 + kb;
                #pragma unroll
                for (int nj = 0; nj < 4; ++nj) {
                    const int kc = wn * 64 + nj * 16 + fr;
                    unsigned char m = m8[mrow + kc];
                    float x = fmaxf(accs[mi][nj][rr] * 0.125f, 0.f);
                    if (!m) rpart[mi][rr] += __expf(x);
                }
            }
    }

    #pragma unroll
    for (int mi = 0; mi < 2; ++mi)
        #pragma unroll
        for (int rr = 0; rr < 4; ++rr) {
            float v = rpart[mi][rr];
            v += __shfl_xor(v, 1);
            v += __shfl_xor(v, 2);
            v += __shfl_xor(v, 4);
            v += __shfl_xor(v, 8);
            if (fr == 0) rs[wn][wm * 32 + mi * 16 + fq * 4 + rr] = v;
        }
    __syncthreads();
    if (t < 64)
        rsg[(size_t)(b * 16 + hh) * 1024 + q0 + t] = 1.f / (rs[0][t] + rs[1][t]);
}

// ---------------------------------------------------------------------------
// attn_b: normalized attention (r6 attn2 minus reduction). Loads inv from rsg,
// writes att = inv*exp directly (f32), PV on normalized bf16 P, byte mask.
// ---------------------------------------------------------------------------
__global__ __launch_bounds__(256) void attn_b(
    const float* __restrict__ qp, const float* __restrict__ kp,
    const float* __restrict__ vp, const unsigned char* __restrict__ m8,
    float* __restrict__ att, u16* __restrict__ omidH, u16* __restrict__ omidL,
    const float* __restrict__ rsg)
{
    extern __shared__ u16 sm16[];
    u16* Qh  = sm16;                       // [64][72]
    u16* Ql  = sm16 + 4608;
    u16* Kh  = sm16 + 9216;                // [128][72]
    u16* Kl  = sm16 + 18432;
    float* Sf = (float*)(sm16 + 9216);     // [64][132] f32 (overlay on K)
    u16* Vth = sm16 + 9216;                // [64][136] (overlay on K)
    u16* Vtl = sm16 + 17920;
    u16* Ps  = sm16 + 27648;               // [64][136]
    float* rs = (float*)(sm16 + 36352);    // [64] = inv

    const int t = threadIdx.x;
    const int lane = t & 63, w = t >> 6;
    const int wm = w >> 1, wn = w & 1;
    const int fr = lane & 15, fq = lane >> 4;
    const int blk = blockIdx.x;
    const int qt = blk & 15, hh = (blk >> 4) & 15, b = blk >> 8;
    const int q0 = qt * 64;

    const size_t qbase  = ((size_t)b * 1024 + q0) * DM + hh * 64;
    const size_t kvbase = ((size_t)b * 1024) * DM + hh * 64;
    const size_t mb8    = ((size_t)b) << 20;
    const size_t abase  = ((size_t)(b * 16 + hh)) << 20;

    if (t < 64) rs[t] = rsg[(size_t)(b * 16 + hh) * 1024 + q0 + t];

    #pragma unroll
    for (int l = 0; l < 4; ++l) {
        int f = t + l * 256;
        int r = f >> 4, dq = f & 15;
        float4 v = ldg4(qp + qbase + (size_t)r * DM + dq * 4);
        u16 hi, lo; ushort4 h4, l4;
        split2(v.x, hi, lo); h4.x = hi; l4.x = lo;
        split2(v.y, hi, lo); h4.y = hi; l4.y = lo;
        split2(v.z, hi, lo); h4.z = hi; l4.z = lo;
        split2(v.w, hi, lo); h4.w = hi; l4.w = lo;
        *reinterpret_cast<ushort4*>(Qh + r * 72 + dq * 4) = h4;
        *reinterpret_cast<ushort4*>(Ql + r * 72 + dq * 4) = l4;
    }

    f32x4 pv[2][2];
    #pragma unroll
    for (int i = 0; i < 2; ++i)
        #pragma unroll
        for (int j = 0; j < 2; ++j)
            pv[i][j] = (f32x4){0.f, 0.f, 0.f, 0.f};

    float4 kreg[8];
    #pragma unroll
    for (int l = 0; l < 8; ++l) {
        int f = t + l * 256;
        int r = f >> 4, dq = f & 15;
        kreg[l] = ldg4(kp + kvbase + (size_t)r * DM + dq * 4);
    }

    for (int kt2 = 0; kt2 < 8; ++kt2) {
        const int kb = kt2 * 128;
        __syncthreads();   // B1: prev PV done (also: rs/Q visible on iter 0)

        #pragma unroll
        for (int l = 0; l < 8; ++l) {
            int f = t + l * 256;
            int r = f >> 4, dq = f & 15;
            float4 v = kreg[l];
            u16 hi, lo; ushort4 h4, l4;
            split2(v.x, hi, lo); h4.x = hi; l4.x = lo;
            split2(v.y, hi, lo); h4.y = hi; l4.y = lo;
            split2(v.z, hi, lo); h4.z = hi; l4.z = lo;
            split2(v.w, hi, lo); h4.w = hi; l4.w = lo;
            *reinterpret_cast<ushort4*>(Kh + r * 72 + dq * 4) = h4;
            *reinterpret_cast<ushort4*>(Kl + r * 72 + dq * 4) = l4;
        }
        __syncthreads();   // B2: K visible

        // prefetch V(kt2) (lands during QK^T)
        float4 vreg[8];
        {
            const int k_ = t >> 1, hd = t & 1;
            const float* src = vp + kvbase + (size_t)(kb + k_) * DM + hd * 32;
            #pragma unroll
            for (int c = 0; c < 8; ++c) vreg[c] = ldg4(src + c * 4);
        }

        f32x4 accs[2][4];
        #pragma unroll
        for (int i = 0; i < 2; ++i)
            #pragma unroll
            for (int j = 0; j < 4; ++j)
                accs[i][j] = (f32x4){0.f, 0.f, 0.f, 0.f};
        #pragma unroll
        for (int kk = 0; kk < 2; ++kk) {
            short8 qh_[2], ql_[2];
            #pragma unroll
            for (int mi = 0; mi < 2; ++mi) {
                const int off = (wm * 32 + mi * 16 + fr) * 72 + kk * 32 + fq * 8;
                qh_[mi] = *reinterpret_cast<const short8*>(Qh + off);
                ql_[mi] = *reinterpret_cast<const short8*>(Ql + off);
            }
            #pragma unroll
            for (int nj = 0; nj < 4; ++nj) {
                const int off = (wn * 64 + nj * 16 + fr) * 72 + kk * 32 + fq * 8;
                short8 kh_ = *reinterpret_cast<const short8*>(Kh + off);
                short8 kl_ = *reinterpret_cast<const short8*>(Kl + off);
                #pragma unroll
                for (int mi = 0; mi < 2; ++mi) {
                    accs[mi][nj] = __builtin_amdgcn_mfma_f32_16x16x32_bf16(qh_[mi], kh_, accs[mi][nj], 0, 0, 0);
                    accs[mi][nj] = __builtin_amdgcn_mfma_f32_16x16x32_bf16(qh_[mi], kl_, accs[mi][nj], 0, 0, 0);
                    accs[mi][nj] = __builtin_amdgcn_mfma_f32_16x16x32_bf16(ql_[mi], kh_, accs[mi][nj], 0, 0, 0);
                }
            }
        }
        __syncthreads();   // B3: K reads done before S overwrite

        #pragma unroll
        for (int mi = 0; mi < 2; ++mi)
            #pragma unroll
            for (int rr = 0; rr < 4; ++rr) {
                const int qrow = wm * 32 + mi * 16 + fq * 4 + rr;
                #pragma unroll
                for (int nj = 0; nj < 4; ++nj)
                    Sf[qrow * 132 + wn * 64 + nj * 16 + fr] = accs[mi][nj][rr];
            }
        __syncthreads();   // B4: S visible

        // coalesced exp phase: normalized write (byte mask, inv preloaded)
        #pragma unroll
        for (int l = 0; l < 8; ++l) {
            const int row = (t >> 5) + l * 8;
            const int gq = q0 + row;
            float4 sv = *reinterpret_cast<const float4*>(Sf + row * 132 + (t & 31) * 4);
            uchar4 mq = *reinterpret_cast<const uchar4*>(
                m8 + mb8 + (size_t)gq * 1024 + kb + (t & 31) * 4);
            const float iv = rs[row];
            float e[4];
            float s4[4] = {sv.x, sv.y, sv.z, sv.w};
            unsigned char m4[4] = {mq.x, mq.y, mq.z, mq.w};
            #pragma unroll
            for (int u = 0; u < 4; ++u) {
                float x = fmaxf(s4[u] * 0.125f, 0.f);
                e[u] = m4[u] ? 0.f : iv * __expf(x);
            }
            float4 ev = {e[0], e[1], e[2], e[3]};
            *reinterpret_cast<float4*>(att + abase + (size_t)gq * 1024 + kb + (t & 31) * 4) = ev;
            ushort4 pp = {bf16rn(e[0]), bf16rn(e[1]), bf16rn(e[2]), bf16rn(e[3])};
            *reinterpret_cast<ushort4*>(Ps + row * 136 + (t & 31) * 4) = pp;
        }
        __syncthreads();   // B5: S reads done before V overwrite; Ps visible

        {
            const int k_ = t >> 1, hd = t & 1;
            #pragma unroll
            for (int c = 0; c < 8; ++c) {
                float4 v = vreg[c];
                const int d0 = hd * 32 + c * 4;
                u16 hi, lo;
                split2(v.x, hi, lo); Vth[(d0+0)*136 + k_] = hi; Vtl[(d0+0)*136 + k_] = lo;
                split2(v.y, hi, lo); Vth[(d0+1)*136 + k_] = hi; Vtl[(d0+1)*136 + k_] = lo;
                split2(v.z, hi, lo); Vth[(d0+2)*136 + k_] = hi; Vtl[(d0+2)*136 + k_] = lo;
                split2(v.w, hi, lo); Vth[(d0+3)*136 + k_] = hi; Vtl[(d0+3)*136 + k_] = lo;
            }
        }
        __syncthreads();   // B6: V visible

        // prefetch K(kt2+1) (lands during PV + next B1)
        {
            const int nkb = (kt2 < 7 ? kt2 + 1 : 7) * 128;
            #pragma unroll
            for (int l = 0; l < 8; ++l) {
                int f = t + l * 256;
                int r = f >> 4, dq = f & 15;
                kreg[l] = ldg4(kp + kvbase + (size_t)(nkb + r) * DM + dq * 4);
            }
        }

        #pragma unroll
        for (int kk = 0; kk < 4; ++kk) {
            short8 pa[2];
            #pragma unroll
            for (int mi = 0; mi < 2; ++mi)
                pa[mi] = *reinterpret_cast<const short8*>(
                    Ps + (wm * 32 + mi * 16 + fr) * 136 + kk * 32 + fq * 8);
            #pragma unroll
            for (int nj = 0; nj < 2; ++nj) {
                const int off = (wn * 32 + nj * 16 + fr) * 136 + kk * 32 + fq * 8;
                short8 vh_ = *reinterpret_cast<const short8*>(Vth + off);
                short8 vl_ = *reinterpret_cast<const short8*>(Vtl + off);
                #pragma unroll
                for (int mi = 0; mi < 2; ++mi) {
                    pv[mi][nj] = __builtin_amdgcn_mfma_f32_16x16x32_bf16(pa[mi], vh_, pv[mi][nj], 0, 0, 0);
                    pv[mi][nj] = __builtin_amdgcn_mfma_f32_16x16x32_bf16(pa[mi], vl_, pv[mi][nj], 0, 0, 0);
                }
            }
        }
    }

    // omid = pv (already normalized), split + swz32 (A-input of output proj)
    #pragma unroll
    for (int mi = 0; mi < 2; ++mi) {
        #pragma unroll
        for (int rr = 0; rr < 4; ++rr) {
            const int qrow = wm * 32 + mi * 16 + fq * 4 + rr;
            const size_t grow = (size_t)b * 1024 + q0 + qrow;
            #pragma unroll
            for (int nj = 0; nj < 2; ++nj) {
                const int d = hh * 64 + wn * 32 + nj * 16 + fr;
                u16 hi, lo;
                split2(pv[mi][nj][rr], hi, lo);
                const size_t off = grow * DM + swz32(qrow, d);
                omidH[off] = hi;
                omidL[off] = lo;
            }
        }
    }
}

extern "C" void kernel_launch(void* const* d_in, const int* in_sizes, int n_in,
                              void* d_out, int out_size, void* d_ws, size_t ws_size,
                              hipStream_t stream)
{
    const float* q    = (const float*)d_in[0];
    const float* k    = (const float*)d_in[1];
    const float* v    = (const float*)d_in[2];
    const float* e    = (const float*)d_in[3];
    const float* mask = (const float*)d_in[4];
    const float* bq   = (const float*)d_in[6];
    const float* bq2  = (const float*)d_in[8];
    const float* bq3  = (const float*)d_in[10];
    const float* bk   = (const float*)d_in[12];
    const float* bk2  = (const float*)d_in[14];
    const float* bk3  = (const float*)d_in[16];
    const float* bv   = (const float*)d_in[18];
    const float* bo   = (const float*)d_in[20];

    float* out = (float*)d_out;                       // 4096*1024 f32
    float* att = out + (size_t)4096 * 1024;           // 65536*1024 f32

    // ws (96.3 MB, same footprint as r5/r6): weights 32MB, qp/kp/vpp 48MB,
    // omid split 16MB, rsg 0.26MB
    u16* WT = (u16*)d_ws;
    const size_t WSZ = 1048576;
    const size_t NA = (size_t)4096 * 1024;
    float* qp   = (float*)(WT + 16 * WSZ);
    float* kp   = qp + NA;
    float* vpp  = kp + NA;
    u16* omidH  = (u16*)(vpp + NA);
    u16* omidL  = omidH + NA;
    float* rsg  = (float*)(omidL + NA);
    // byte-mask lives over weight-0's hi/lo pair (4 MB, dead after dispatch A)
    unsigned char* m8 = (unsigned char*)WT;

    // att-region scratch (117.6MB <= 268MB, dead before attn_b writes att)
    u16* AR   = (u16*)att;
    u16* QspH = AR;            u16* QspL = QspH + NA;
    u16* E1H  = QspL + NA;     u16* E1L  = E1H + NA;
    u16* KspH = E1L + NA;      u16* KspL = KspH + NA;
    u16* E0H  = KspL + NA;     u16* E0L  = E0H + NA;
    u16* VsH  = E0L + NA;      u16* VsL  = VsH + NA;
    u16* tQH  = VsL + NA;      u16* tQL  = tQH + NA;
    u16* tKH  = tQL + NA;      u16* tKL  = tKH + NA;

    // activation pre-split
    PJobs pj;
    pj.j[0] = PJob{q, 1025, 1, QspH, QspL};
    pj.j[1] = PJob{e, 1025, 1, E1H, E1L};
    pj.j[2] = PJob{k, 1025, 0, KspH, KspL};
    pj.j[3] = PJob{e, 1025, 0, E0H, E0L};
    pj.j[4] = PJob{v, 1024, 0, VsH, VsL};
    prep_k<<<dim3(5 * 4096), 256, 0, stream>>>(pj);

    // weight conversion
    WPack wp;
    #pragma unroll
    for (int i = 0; i < 8; ++i) {
        wp.in[i] = (const float*)d_in[5 + 2 * i];
        wp.hi[i] = WT + (size_t)i * 2 * WSZ;
        wp.lo[i] = WT + (size_t)i * 2 * WSZ + WSZ;
    }
    convw_k<<<dim3(1024, 8), 256, 0, stream>>>(wp);

    hipFuncSetAttribute((const void*)gemm7, hipFuncAttributeMaxDynamicSharedMemorySize, 131072);

    // Dispatch A (192 blocks): q1 (dual K-concat, leaky, split-out), k1, v
    GJobs JA;
    JA.j[0] = GJob{QspH, QspL, E1H, E1L, wp.hi[0], wp.lo[0], wp.hi[1], wp.lo[1],
                   bq, bq2, nullptr, tQH, tQL, 64, 1, 1, 1};
    JA.j[1] = GJob{KspH, KspL, E0H, E0L, wp.hi[3], wp.lo[3], wp.hi[4], wp.lo[4],
                   bk, bk2, nullptr, tKH, tKL, 64, 1, 1, 1};
    JA.j[2] = GJob{VsH, VsL, nullptr, nullptr, wp.hi[6], wp.lo[6], nullptr, nullptr,
                   bv, nullptr, vpp, nullptr, nullptr, 32, 0, 0, 0};
    gemm7<<<dim3(192), 512, 131072, stream>>>(JA);

    // byte-mask prep (overwrites W0's region — W0/W1 dead after dispatch A)
    mprep_k<<<dim3(4096), 256, 0, stream>>>(mask, m8);

    // Dispatch B (128 blocks): q2, k2
    GJobs JB;
    JB.j[0] = GJob{tQH, tQL, nullptr, nullptr, wp.hi[2], wp.lo[2], nullptr, nullptr,
                   bq3, nullptr, qp, nullptr, nullptr, 32, 0, 0, 0};
    JB.j[1] = GJob{tKH, tKL, nullptr, nullptr, wp.hi[5], wp.lo[5], nullptr, nullptr,
                   bk3, nullptr, kp, nullptr, nullptr, 32, 0, 0, 0};
    JB.j[2] = JB.j[0];
    gemm7<<<dim3(128), 512, 131072, stream>>>(JB);

    // attention: rowsums, then normalized attention
    attn_a<<<dim3(1024), 256, 0, stream>>>(qp, kp, m8, rsg);

    const int smemA = 72960;
    hipFuncSetAttribute((const void*)attn_b, hipFuncAttributeMaxDynamicSharedMemorySize, smemA);
    attn_b<<<dim3(1024), 256, smemA, stream>>>(qp, kp, vpp, m8, att, omidH, omidL, rsg);

    // Dispatch C (64 blocks): output projection
    GJobs JC;
    JC.j[0] = GJob{omidH, omidL, nullptr, nullptr, wp.hi[7], wp.lo[7], nullptr, nullptr,
                   bo, nullptr, out, nullptr, nullptr, 32, 0, 0, 0};
    JC.j[1] = JC.j[0];
    JC.j[2] = JC.j[0];
    gemm7<<<dim3(64), 512, 131072, stream>>>(JC);
}